// Round 4
// baseline (179.420 us; speedup 1.0000x reference)
//
#include <hip/hip_runtime.h>
#include <hip/hip_bf16.h>
#include <stdint.h>

typedef unsigned short u16;
typedef __bf16 bf16x8 __attribute__((ext_vector_type(8)));
typedef float f32x4 __attribute__((ext_vector_type(4)));

// E=8, D=512, H=256, T=64, B=16384

#define SBAR __builtin_amdgcn_s_barrier()
#define SCHEDB __builtin_amdgcn_sched_barrier(0)
#define WAIT_V8 asm volatile("s_waitcnt vmcnt(8) lgkmcnt(0)" ::: "memory")
#define WAIT_V0 asm volatile("s_waitcnt vmcnt(0) lgkmcnt(0)" ::: "memory")

__device__ __forceinline__ void glds16(const void* g, void* l) {
  __builtin_amdgcn_global_load_lds(
      (const __attribute__((address_space(1))) unsigned int*)g,
      (__attribute__((address_space(3))) unsigned int*)l, 16, 0, 0);
}

__device__ __forceinline__ u16 f2bf(float f) {
  unsigned int u = __builtin_bit_cast(unsigned int, f);
  u += 0x7fffu + ((u >> 16) & 1u);   // RNE (finite inputs)
  return (u16)(u >> 16);
}

// ---------------- prep: weight conversion only ----------------
__global__ __launch_bounds__(256) void prep_w(
    const float* __restrict__ We, const float* __restrict__ Wt,
    const float* __restrict__ Wg,
    u16* __restrict__ We_bf, u16* __restrict__ Wt_bf,
    u16* __restrict__ Wg_hi, u16* __restrict__ Wg_lo) {
  const int bx = blockIdx.x;
  if (bx < 520) {
    const float* src; u16* dst;
    if (bx < 512) { int base = bx * 2048 + threadIdx.x * 8; src = We + base; dst = We_bf + base; }
    else { int base = (bx - 512) * 2048 + threadIdx.x * 8; src = Wt + base; dst = Wt_bf + base; }
    float4 a = *(const float4*)src;
    float4 b = *(const float4*)(src + 4);
    uint4 o;
    o.x = (unsigned)f2bf(a.x) | ((unsigned)f2bf(a.y) << 16);
    o.y = (unsigned)f2bf(a.z) | ((unsigned)f2bf(a.w) << 16);
    o.z = (unsigned)f2bf(b.x) | ((unsigned)f2bf(b.y) << 16);
    o.w = (unsigned)f2bf(b.z) | ((unsigned)f2bf(b.w) << 16);
    *(uint4*)dst = o;
  } else {
    int base = (bx - 520) * 2048 + threadIdx.x * 8;
    float x[8];
    float4 a = *(const float4*)(Wg + base);
    float4 b = *(const float4*)(Wg + base + 4);
    x[0]=a.x; x[1]=a.y; x[2]=a.z; x[3]=a.w; x[4]=b.x; x[5]=b.y; x[6]=b.z; x[7]=b.w;
    u16 h[8], l[8];
#pragma unroll
    for (int j = 0; j < 8; j++) {
      h[j] = f2bf(x[j]);
      float hf = __builtin_bit_cast(float, ((unsigned)h[j]) << 16);
      l[j] = f2bf(x[j] - hf);
    }
    uint4 oh, ol;
    oh.x = (unsigned)h[0] | ((unsigned)h[1] << 16);
    oh.y = (unsigned)h[2] | ((unsigned)h[3] << 16);
    oh.z = (unsigned)h[4] | ((unsigned)h[5] << 16);
    oh.w = (unsigned)h[6] | ((unsigned)h[7] << 16);
    ol.x = (unsigned)l[0] | ((unsigned)l[1] << 16);
    ol.y = (unsigned)l[2] | ((unsigned)l[3] << 16);
    ol.z = (unsigned)l[4] | ((unsigned)l[5] << 16);
    ol.w = (unsigned)l[6] | ((unsigned)l[7] << 16);
    *(uint4*)(Wg_hi + base) = oh;
    *(uint4*)(Wg_lo + base) = ol;
  }
}

// stage one B chunk (256 h-rows x 128 k, bf16) into ldsbuf via glds16,
// 16B-granule xor-swizzled source (slot s of row n holds granule (s&8)|((s&7)^(n&7)))
// Exactly 8 glds16 per thread per call -> vmcnt counting unit = 8.
__device__ __forceinline__ void stage_chunk(const u16* __restrict__ We_bf,
                                            u16* ldsbuf, int t, int tid) {
  const int e_ = t >> 2, kc_ = t & 3;
  const u16* src = We_bf + (e_ << 17) + (kc_ << 7);
#pragma unroll
  for (int r = 0; r < 8; r++) {
    int gi = r * 512 + tid;             // 0..4095
    int n = gi >> 4, s = gi & 15;
    int g = (s & 8) | ((s & 7) ^ (n & 7));
    glds16(src + (n << 9) + (g << 3), ldsbuf + (gi << 3));
  }
}

// ---------------- fused main kernel ----------------
// grid = 256 (64-row m-tiles, FULL H=256 per block), 512 threads = 8 waves (2x4).
// A (xv) in registers (bf16 frags). B (We) streams through double-buffered
// swizzled LDS with a COUNTED-vmcnt schedule (T3/T4): raw s_barrier, never
// vmcnt(0) in the main loop -> next chunk's 8 global_load_lds stay in flight
// across both barriers. be lives in LDS so the loop contains NO other VMEM
// (keeps vmcnt arithmetic exact). RULE #20: all ah indices compile-time.
// 8-wave block -> hard cap 256 regs/wave (2 waves/SIMD); steady need ~245.
__global__ __launch_bounds__(512, 1) void moe_main(
    const float* __restrict__ xv, const u16* __restrict__ We_bf,
    const float* __restrict__ be, const float* __restrict__ bg,
    const u16* __restrict__ Wg_hi, const u16* __restrict__ Wg_lo,
    const u16* __restrict__ Wt_bf, const float* __restrict__ bt,
    float* __restrict__ out) {
  __shared__ u16 lds[69632];            // 128 KB B bufs + 8 KB be (f32)
  float* beL = (float*)&lds[65536];

  const int tid = threadIdx.x;
  const int lane = tid & 63;
  const int wid = tid >> 6;             // 0..7
  const int wm = wid >> 2;              // 0..1  (32-row band)
  const int wn = wid & 3;               // 0..3  (64-col band)
  const int l15 = lane & 15;
  const int l4 = lane >> 4;             // 0..3
  const int m0 = blockIdx.x << 6;

  // prologue staging: chunks 0 and 1 land while the A/gate prologue runs
  stage_chunk(We_bf, lds, 0, tid);
  *(float4*)(beL + (tid << 2)) = *(const float4*)(be + (tid << 2));
  stage_chunk(We_bf, &lds[32768], 1, tid);

  // ---- A load (f32 -> bf16 frags in regs) + gate logits via hi/lo MFMA ----
  // sched_barrier every 4 ks: caps hoisting (~32 live f32) but keeps 8 loads
  // in flight for HBM latency. 3 gate accumulator chains (shorter dep chains).
  bf16x8 ah[2][16];                     // 128 VGPR: 32 rows x K=512
  f32x4 g0[2] = {{0.f,0.f,0.f,0.f},{0.f,0.f,0.f,0.f}};
  f32x4 g1[2] = {{0.f,0.f,0.f,0.f},{0.f,0.f,0.f,0.f}};
  f32x4 g2[2] = {{0.f,0.f,0.f,0.f},{0.f,0.f,0.f,0.f}};
  const int esrc = l15 & 7;
#pragma unroll
  for (int mt = 0; mt < 2; mt++) {
#pragma unroll
    for (int ks = 0; ks < 16; ks++) {   // FULL unroll: ah index stays constant
      const float* ap = xv + ((m0 + wm * 32 + mt * 16 + l15) << 9) + ks * 32 + l4 * 8;
      float4 xa = *(const float4*)ap;
      float4 xb = *(const float4*)(ap + 4);
      float x[8];
      x[0]=xa.x; x[1]=xa.y; x[2]=xa.z; x[3]=xa.w; x[4]=xb.x; x[5]=xb.y; x[6]=xb.z; x[7]=xb.w;
      bf16x8 hv, lv;
#pragma unroll
      for (int j = 0; j < 8; j++) {
        u16 hb_ = f2bf(x[j]);
        float hf = __builtin_bit_cast(float, ((unsigned)hb_) << 16);
        hv[j] = __builtin_bit_cast(__bf16, hb_);
        lv[j] = __builtin_bit_cast(__bf16, f2bf(x[j] - hf));
      }
      ah[mt][ks] = hv;
      bf16x8 wh = *(const bf16x8*)(Wg_hi + (esrc << 9) + ks * 32 + l4 * 8);
      bf16x8 wl = *(const bf16x8*)(Wg_lo + (esrc << 9) + ks * 32 + l4 * 8);
      g0[mt] = __builtin_amdgcn_mfma_f32_16x16x32_bf16(hv, wh, g0[mt], 0, 0, 0);
      g1[mt] = __builtin_amdgcn_mfma_f32_16x16x32_bf16(lv, wh, g1[mt], 0, 0, 0);
      g2[mt] = __builtin_amdgcn_mfma_f32_16x16x32_bf16(hv, wl, g2[mt], 0, 0, 0);
      if ((ks & 3) == 3) SCHEDB;
    }
  }
  // softmax over experts: lane holds logit[row=l4*4+i][e=l15&7]; 8-lane reduce
  float gv[2][4];
  {
    float bgv = bg[esrc];
#pragma unroll
    for (int mt = 0; mt < 2; mt++)
#pragma unroll
      for (int i = 0; i < 4; i++) {
        float z = g0[mt][i] + g1[mt][i] + g2[mt][i] + bgv;
        float mx = z;
        mx = fmaxf(mx, __shfl_xor(mx, 1));
        mx = fmaxf(mx, __shfl_xor(mx, 2));
        mx = fmaxf(mx, __shfl_xor(mx, 4));
        float p = __expf(z - mx);
        float s = p;
        s += __shfl_xor(s, 1);
        s += __shfl_xor(s, 2);
        s += __shfl_xor(s, 4);
        gv[mt][i] = p / s;
      }
  }
  SCHEDB;

  // ---- expert loop: counted-vmcnt double-buffered B stream ----
  f32x4 comb[2][4];
#pragma unroll
  for (int mt = 0; mt < 2; mt++)
#pragma unroll
    for (int nt = 0; nt < 4; nt++) comb[mt][nt] = {0.f, 0.f, 0.f, 0.f};

#pragma unroll 1
  for (int e = 0; e < 8; e++) {
    f32x4 acc[2][4];
#pragma unroll
    for (int mt = 0; mt < 2; mt++)
#pragma unroll
      for (int nt = 0; nt < 4; nt++) acc[mt][nt] = {0.f, 0.f, 0.f, 0.f};

#pragma unroll
    for (int kc = 0; kc < 4; kc++) {    // chunk c = e*4+kc; buffer = kc&1
      // wait for chunk c's 8 loads; chunk c+1's 8 stay in flight (vmcnt(8)).
      // Only the very last chunk needs a full drain.
      if (kc == 3) {
        if (e == 7) { WAIT_V0; } else { WAIT_V8; }
      } else {
        WAIT_V8;
      }
      SBAR;                             // all waves' chunk-c data visible
      SCHEDB;
      const u16* ldsB = &lds[(kc & 1) << 15];
#pragma unroll
      for (int ks = 0; ks < 4; ks++) {
        const int gg = ks * 4 + l4;
        bf16x8 bfr[4];
#pragma unroll
        for (int nt = 0; nt < 4; nt++) {
          int n = wn * 64 + nt * 16 + l15;
          int slot = (gg & 8) | ((gg & 7) ^ (n & 7));
          bfr[nt] = *(const bf16x8*)&ldsB[(n << 7) + (slot << 3)];
        }
#pragma unroll
        for (int mt = 0; mt < 2; mt++)
#pragma unroll
          for (int nt = 0; nt < 4; nt++)
            acc[mt][nt] = __builtin_amdgcn_mfma_f32_16x16x32_bf16(
                ah[mt][kc * 4 + ks], bfr[nt], acc[mt][nt], 0, 0, 0);
      }
      SBAR;                             // all waves done reading buf[kc&1]
      SCHEDB;
      int t2 = e * 4 + kc + 2;
      if (t2 < 32) stage_chunk(We_bf, &lds[(kc & 1) << 15], t2, tid);
    }
    // fold: comb += gate[row,e] * relu(acc + be[e,h]) — VALU+LDS only
    // (be from LDS keeps the loop free of extra VMEM; also covers stage latency)
    float bev[4];
#pragma unroll
    for (int nt = 0; nt < 4; nt++)
      bev[nt] = beL[(e << 8) + wn * 64 + nt * 16 + l15];
#pragma unroll
    for (int mt = 0; mt < 2; mt++)
#pragma unroll
      for (int i = 0; i < 4; i++) {
        float g = __shfl(gv[mt][i], (lane & 48) | e);
#pragma unroll
        for (int nt = 0; nt < 4; nt++)
          comb[mt][nt][i] += g * fmaxf(acc[mt][nt][i] + bev[nt], 0.f);
      }
  }

  // ---- tower: comb[64x256] (bf16 via LDS) x Wt^T -> sigmoid -> out ----
  // All stages retired (last chunk drained vmcnt(0)); barriers passed.
#pragma unroll
  for (int mt = 0; mt < 2; mt++)
#pragma unroll
    for (int i = 0; i < 4; i++) {
      int row = wm * 32 + mt * 16 + l4 * 4 + i;
#pragma unroll
      for (int nt = 0; nt < 4; nt++) {
        int col = wn * 64 + nt * 16 + l15;
        __bf16 v = (__bf16)comb[mt][nt][i];
        lds[row * 264 + col] = __builtin_bit_cast(u16, v);   // pad 264
      }
    }
  __syncthreads();
  if (wid < 4) {
    f32x4 tacc[4];
#pragma unroll
    for (int nt = 0; nt < 4; nt++) tacc[nt] = {0.f, 0.f, 0.f, 0.f};
#pragma unroll
    for (int ks = 0; ks < 8; ks++) {
      bf16x8 aT = *(const bf16x8*)&lds[(wid * 16 + l15) * 264 + ks * 32 + l4 * 8];
#pragma unroll
      for (int nt = 0; nt < 4; nt++) {
        bf16x8 bT = *(const bf16x8*)&Wt_bf[(nt * 16 + l15) * 256 + ks * 32 + l4 * 8];
        tacc[nt] = __builtin_amdgcn_mfma_f32_16x16x32_bf16(aT, bT, tacc[nt], 0, 0, 0);
      }
    }
#pragma unroll
    for (int nt = 0; nt < 4; nt++) {
      float btv = bt[nt * 16 + l15];
#pragma unroll
      for (int i = 0; i < 4; i++) {
        int row = m0 + wid * 16 + l4 * 4 + i;
        float v = tacc[nt][i] + btv;
        out[row * 64 + nt * 16 + l15] = 1.f / (1.f + __expf(-v));
      }
    }
  }
}

extern "C" void kernel_launch(void* const* d_in, const int* in_sizes, int n_in,
                              void* d_out, int out_size, void* d_ws, size_t ws_size,
                              hipStream_t stream) {
  const float* xv = (const float*)d_in[0];
  const float* We = (const float*)d_in[1];
  const float* be = (const float*)d_in[2];
  const float* Wg = (const float*)d_in[3];
  const float* bg = (const float*)d_in[4];
  const float* Wt = (const float*)d_in[5];
  const float* bt = (const float*)d_in[6];

  char* ws = (char*)d_ws;
  u16* We_bf = (u16*)ws;                        // 2 MB   (8*256*512 bf16)
  u16* Wt_bf = (u16*)(ws + 2097152);            // 32 KB  (64*256 bf16)
  u16* Wg_hi = (u16*)(ws + 2129920);            // 8 KB   (8*512 bf16)
  u16* Wg_lo = (u16*)(ws + 2138112);            // 8 KB

  prep_w<<<522, 256, 0, stream>>>(We, Wt, Wg, We_bf, Wt_bf, Wg_hi, Wg_lo);
  moe_main<<<256, 512, 0, stream>>>(xv, We_bf, be, bg, Wg_hi, Wg_lo, Wt_bf, bt,
                                    (float*)d_out);
}

// Round 5
// 177.872 us; speedup vs baseline: 1.0087x; 1.0087x over previous
//
#include <hip/hip_runtime.h>
#include <hip/hip_bf16.h>
#include <stdint.h>

typedef unsigned short u16;
typedef __bf16 bf16x8 __attribute__((ext_vector_type(8)));
typedef float f32x4 __attribute__((ext_vector_type(4)));

// E=8, D=512, H=256, T=64, B=16384

__device__ __forceinline__ void glds16(const void* g, void* l) {
  __builtin_amdgcn_global_load_lds(
      (const __attribute__((address_space(1))) unsigned int*)g,
      (__attribute__((address_space(3))) unsigned int*)l, 16, 0, 0);
}

__device__ __forceinline__ u16 f2bf(float f) {
  unsigned int u = __builtin_bit_cast(unsigned int, f);
  u += 0x7fffu + ((u >> 16) & 1u);   // RNE (finite inputs)
  return (u16)(u >> 16);
}

// ---------------- prep: weight conversion only ----------------
__global__ __launch_bounds__(256) void prep_w(
    const float* __restrict__ We, const float* __restrict__ Wt,
    const float* __restrict__ Wg,
    u16* __restrict__ We_bf, u16* __restrict__ Wt_bf,
    u16* __restrict__ Wg_hi, u16* __restrict__ Wg_lo) {
  const int bx = blockIdx.x;
  if (bx < 520) {
    const float* src; u16* dst;
    if (bx < 512) { int base = bx * 2048 + threadIdx.x * 8; src = We + base; dst = We_bf + base; }
    else { int base = (bx - 512) * 2048 + threadIdx.x * 8; src = Wt + base; dst = Wt_bf + base; }
    float4 a = *(const float4*)src;
    float4 b = *(const float4*)(src + 4);
    uint4 o;
    o.x = (unsigned)f2bf(a.x) | ((unsigned)f2bf(a.y) << 16);
    o.y = (unsigned)f2bf(a.z) | ((unsigned)f2bf(a.w) << 16);
    o.z = (unsigned)f2bf(b.x) | ((unsigned)f2bf(b.y) << 16);
    o.w = (unsigned)f2bf(b.z) | ((unsigned)f2bf(b.w) << 16);
    *(uint4*)dst = o;
  } else {
    int base = (bx - 520) * 2048 + threadIdx.x * 8;
    float x[8];
    float4 a = *(const float4*)(Wg + base);
    float4 b = *(const float4*)(Wg + base + 4);
    x[0]=a.x; x[1]=a.y; x[2]=a.z; x[3]=a.w; x[4]=b.x; x[5]=b.y; x[6]=b.z; x[7]=b.w;
    u16 h[8], l[8];
#pragma unroll
    for (int j = 0; j < 8; j++) {
      h[j] = f2bf(x[j]);
      float hf = __builtin_bit_cast(float, ((unsigned)h[j]) << 16);
      l[j] = f2bf(x[j] - hf);
    }
    uint4 oh, ol;
    oh.x = (unsigned)h[0] | ((unsigned)h[1] << 16);
    oh.y = (unsigned)h[2] | ((unsigned)h[3] << 16);
    oh.z = (unsigned)h[4] | ((unsigned)h[5] << 16);
    oh.w = (unsigned)h[6] | ((unsigned)h[7] << 16);
    ol.x = (unsigned)l[0] | ((unsigned)l[1] << 16);
    ol.y = (unsigned)l[2] | ((unsigned)l[3] << 16);
    ol.z = (unsigned)l[4] | ((unsigned)l[5] << 16);
    ol.w = (unsigned)l[6] | ((unsigned)l[7] << 16);
    *(uint4*)(Wg_hi + base) = oh;
    *(uint4*)(Wg_lo + base) = ol;
  }
}

// stage one B chunk (256 h-rows x 64 k, bf16, 32 KB) into ldsbuf via glds16.
// LDS layout per row n: 8 granules of 16B; linear slot s holds SOURCE granule
// g = s ^ (n&7) (pre-swizzled global address, LDS dest stays linear — m173).
// Reader computes slot = g ^ (n&7). 8 glds16 per thread per call.
__device__ __forceinline__ void stage_chunk(const u16* __restrict__ We_bf,
                                            u16* ldsbuf, int t, int tid) {
  const int e_ = t >> 3, kc_ = t & 7;
  const u16* src = We_bf + (e_ << 17) + (kc_ << 6);
#pragma unroll
  for (int r = 0; r < 8; r++) {
    int gi = r * 256 + tid;             // 0..2047 granules
    int n = gi >> 3, s = gi & 7;
    int g = s ^ (n & 7);
    glds16(src + (n << 9) + (g << 3), ldsbuf + (gi << 3));
  }
}

// ---------------- fused main kernel ----------------
// grid = 512 (32-row m-tiles, FULL H=256 per block), 256 threads = 4 waves
// (1m x 4n: each wave owns a 64-col band -> B-frag LDS reads have NO wave
// duplication). LDS = 2x32KB B double-buffer + 8KB be = 72KB -> 2 blocks/CU:
// one block's barrier/stage stalls overlap the other's MFMA (the r3/r4
// 1-block/CU lockstep had no such overlap; MfmaUtil was pinned at ~17%).
// Schedule = r3's simple stage-then-compute with __syncthreads (r4's
// counted-vmcnt + sched_barrier REGRESSED: m141 order-pinning effect).
// A (xv) in registers; RULE #20: all ah indices compile-time (full unroll).
__global__ __launch_bounds__(256, 2) void moe_main(
    const float* __restrict__ xv, const u16* __restrict__ We_bf,
    const float* __restrict__ be, const float* __restrict__ bg,
    const u16* __restrict__ Wg_hi, const u16* __restrict__ Wg_lo,
    const u16* __restrict__ Wt_bf, const float* __restrict__ bt,
    float* __restrict__ out) {
  __shared__ u16 lds[36864];            // 64 KB B bufs + 8 KB be (f32)
  float* beL = (float*)&lds[32768];

  const int tid = threadIdx.x;
  const int lane = tid & 63;
  const int wid = tid >> 6;             // 0..3 = wn (64-col band)
  const int wn = wid;
  const int l15 = lane & 15;
  const int l4 = lane >> 4;             // 0..3
  const int m0 = blockIdx.x << 5;       // 32 rows per block

  // prologue staging: chunks 0,1 land while the A/gate prologue runs
  stage_chunk(We_bf, lds, 0, tid);
  *(float4*)(beL + (tid << 3)) = *(const float4*)(be + (tid << 3));
  *(float4*)(beL + (tid << 3) + 4) = *(const float4*)(be + (tid << 3) + 4);
  stage_chunk(We_bf, &lds[16384], 1, tid);

  // ---- A load (f32 -> bf16 frags in regs) + gate logits via hi/lo MFMA ----
  bf16x8 ah[2][16];                     // 128 VGPR: 32 rows x K=512
  f32x4 g0[2] = {{0.f,0.f,0.f,0.f},{0.f,0.f,0.f,0.f}};
  f32x4 g1[2] = {{0.f,0.f,0.f,0.f},{0.f,0.f,0.f,0.f}};
  f32x4 g2[2] = {{0.f,0.f,0.f,0.f},{0.f,0.f,0.f,0.f}};
  const int esrc = l15 & 7;
#pragma unroll
  for (int mt = 0; mt < 2; mt++) {
#pragma unroll
    for (int ks = 0; ks < 16; ks++) {   // FULL unroll: ah index stays constant
      const float* ap = xv + ((m0 + mt * 16 + l15) << 9) + ks * 32 + l4 * 8;
      float4 xa = *(const float4*)ap;
      float4 xb = *(const float4*)(ap + 4);
      float x[8];
      x[0]=xa.x; x[1]=xa.y; x[2]=xa.z; x[3]=xa.w; x[4]=xb.x; x[5]=xb.y; x[6]=xb.z; x[7]=xb.w;
      bf16x8 hv, lv;
#pragma unroll
      for (int j = 0; j < 8; j++) {
        u16 hb_ = f2bf(x[j]);
        float hf = __builtin_bit_cast(float, ((unsigned)hb_) << 16);
        hv[j] = __builtin_bit_cast(__bf16, hb_);
        lv[j] = __builtin_bit_cast(__bf16, f2bf(x[j] - hf));
      }
      ah[mt][ks] = hv;
      bf16x8 wh = *(const bf16x8*)(Wg_hi + (esrc << 9) + ks * 32 + l4 * 8);
      bf16x8 wl = *(const bf16x8*)(Wg_lo + (esrc << 9) + ks * 32 + l4 * 8);
      g0[mt] = __builtin_amdgcn_mfma_f32_16x16x32_bf16(hv, wh, g0[mt], 0, 0, 0);
      g1[mt] = __builtin_amdgcn_mfma_f32_16x16x32_bf16(lv, wh, g1[mt], 0, 0, 0);
      g2[mt] = __builtin_amdgcn_mfma_f32_16x16x32_bf16(hv, wl, g2[mt], 0, 0, 0);
    }
  }
  // softmax over experts: lane holds logit[row=l4*4+i (tile mt)][e=l15&7]
  float gv[2][4];
  {
    float bgv = bg[esrc];
#pragma unroll
    for (int mt = 0; mt < 2; mt++)
#pragma unroll
      for (int i = 0; i < 4; i++) {
        float z = g0[mt][i] + g1[mt][i] + g2[mt][i] + bgv;
        float mx = z;
        mx = fmaxf(mx, __shfl_xor(mx, 1));
        mx = fmaxf(mx, __shfl_xor(mx, 2));
        mx = fmaxf(mx, __shfl_xor(mx, 4));
        float p = __expf(z - mx);
        float s = p;
        s += __shfl_xor(s, 1);
        s += __shfl_xor(s, 2);
        s += __shfl_xor(s, 4);
        gv[mt][i] = p / s;
      }
  }

  // ---- expert loop: B streams through double-buffered LDS, A from regs ----
  f32x4 comb[2][4];
#pragma unroll
  for (int mt = 0; mt < 2; mt++)
#pragma unroll
    for (int nt = 0; nt < 4; nt++) comb[mt][nt] = {0.f, 0.f, 0.f, 0.f};

#pragma unroll 1
  for (int e = 0; e < 8; e++) {
    f32x4 acc[2][4];
#pragma unroll
    for (int mt = 0; mt < 2; mt++)
#pragma unroll
      for (int nt = 0; nt < 4; nt++) acc[mt][nt] = {0.f, 0.f, 0.f, 0.f};

#pragma unroll
    for (int kc = 0; kc < 8; kc++) {    // chunk t = e*8+kc; buffer = t&1
      int t = e * 8 + kc;
      __syncthreads();                  // chunk t staged + chunk t-1 reads done
      if (t + 1 >= 2 && t + 1 < 64)     // 0,1 pre-staged in prologue
        stage_chunk(We_bf, &lds[((t & 1) ^ 1) << 14], t + 1, tid);
      const u16* ldsB = &lds[(t & 1) << 14];
#pragma unroll
      for (int ks = 0; ks < 2; ks++) {
        bf16x8 bfr[4];
#pragma unroll
        for (int nt = 0; nt < 4; nt++) {
          int n = wn * 64 + nt * 16 + l15;
          int g = ks * 4 + l4;
          int slot = g ^ (n & 7);
          bfr[nt] = *(const bf16x8*)&ldsB[(n << 6) + (slot << 3)];
        }
#pragma unroll
        for (int mt = 0; mt < 2; mt++)
#pragma unroll
          for (int nt = 0; nt < 4; nt++)
            acc[mt][nt] = __builtin_amdgcn_mfma_f32_16x16x32_bf16(
                ah[mt][kc * 2 + ks], bfr[nt], acc[mt][nt], 0, 0, 0);
      }
    }
    // fold: comb += gate[row,e] * relu(acc + be[e,h]) — VALU+LDS only
    float bev[4];
#pragma unroll
    for (int nt = 0; nt < 4; nt++)
      bev[nt] = beL[(e << 8) + wn * 64 + nt * 16 + l15];
#pragma unroll
    for (int mt = 0; mt < 2; mt++)
#pragma unroll
      for (int i = 0; i < 4; i++) {
        float g = __shfl(gv[mt][i], (lane & 48) | e);
#pragma unroll
        for (int nt = 0; nt < 4; nt++)
          comb[mt][nt][i] += g * fmaxf(acc[mt][nt][i] + bev[nt], 0.f);
      }
  }

  // ---- tower: comb[32x256] (bf16 via LDS) x Wt^T -> sigmoid -> out ----
  // Last chunk (63) lived in buf1; comb goes to buf0 region — no overlap,
  // so write needs no pre-barrier; one sync before the tower reads.
#pragma unroll
  for (int mt = 0; mt < 2; mt++)
#pragma unroll
    for (int i = 0; i < 4; i++) {
      int row = mt * 16 + l4 * 4 + i;
#pragma unroll
      for (int nt = 0; nt < 4; nt++) {
        int col = wn * 64 + nt * 16 + l15;
        __bf16 v = (__bf16)comb[mt][nt][i];
        lds[row * 264 + col] = __builtin_bit_cast(u16, v);   // pad 264
      }
    }
  __syncthreads();
  if (wid < 2) {
    f32x4 tacc[4];
#pragma unroll
    for (int nt = 0; nt < 4; nt++) tacc[nt] = {0.f, 0.f, 0.f, 0.f};
#pragma unroll
    for (int ks = 0; ks < 8; ks++) {
      bf16x8 aT = *(const bf16x8*)&lds[(wid * 16 + l15) * 264 + ks * 32 + l4 * 8];
#pragma unroll
      for (int nt = 0; nt < 4; nt++) {
        bf16x8 bT = *(const bf16x8*)&Wt_bf[(nt * 16 + l15) * 256 + ks * 32 + l4 * 8];
        tacc[nt] = __builtin_amdgcn_mfma_f32_16x16x32_bf16(aT, bT, tacc[nt], 0, 0, 0);
      }
    }
#pragma unroll
    for (int nt = 0; nt < 4; nt++) {
      float btv = bt[nt * 16 + l15];
#pragma unroll
      for (int i = 0; i < 4; i++) {
        int row = m0 + wid * 16 + l4 * 4 + i;
        float v = tacc[nt][i] + btv;
        out[row * 64 + nt * 16 + l15] = 1.f / (1.f + __expf(-v));
      }
    }
  }
}

extern "C" void kernel_launch(void* const* d_in, const int* in_sizes, int n_in,
                              void* d_out, int out_size, void* d_ws, size_t ws_size,
                              hipStream_t stream) {
  const float* xv = (const float*)d_in[0];
  const float* We = (const float*)d_in[1];
  const float* be = (const float*)d_in[2];
  const float* Wg = (const float*)d_in[3];
  const float* bg = (const float*)d_in[4];
  const float* Wt = (const float*)d_in[5];
  const float* bt = (const float*)d_in[6];

  char* ws = (char*)d_ws;
  u16* We_bf = (u16*)ws;                        // 2 MB   (8*256*512 bf16)
  u16* Wt_bf = (u16*)(ws + 2097152);            // 32 KB  (64*256 bf16)
  u16* Wg_hi = (u16*)(ws + 2129920);            // 8 KB   (8*512 bf16)
  u16* Wg_lo = (u16*)(ws + 2138112);            // 8 KB

  prep_w<<<522, 256, 0, stream>>>(We, Wt, Wg, We_bf, Wt_bf, Wg_hi, Wg_lo);
  moe_main<<<512, 256, 0, stream>>>(xv, We_bf, be, bg, Wg_hi, Wg_lo, Wt_bf, bt,
                                    (float*)d_out);
}

// Round 7
// 152.747 us; speedup vs baseline: 1.1746x; 1.1645x over previous
//
#include <hip/hip_runtime.h>
#include <hip/hip_bf16.h>
#include <stdint.h>

typedef unsigned short u16;
typedef __bf16 bf16x8 __attribute__((ext_vector_type(8)));
typedef float f32x4 __attribute__((ext_vector_type(4)));

// E=8, D=512, H=256, T=64, B=16384

// fused wait+barrier: single asm block so no LDS op can slip between the
// counted vmcnt and the barrier (cross-wave publish of glds16 data).
// COUNT DERIVATION (r6 bug post-mortem): at the WAIT before computing chunk
// t, ops issued after chunk t's 4 glds16 = chunk t+1's 4 ONLY (t+2 is staged
// after the wait). Proving "chunk t retired" therefore needs vmcnt(4);
// vmcnt(8) admits chunk t itself still in flight -> the r6 race (absmax
// 2.3e-2). Depth-2 prefetch still holds DURING compute (t+1,t+2 in flight).
#define BAR_V4 asm volatile("s_waitcnt vmcnt(4)\ns_barrier" ::: "memory")
#define BAR_V0 asm volatile("s_waitcnt vmcnt(0)\ns_barrier" ::: "memory")

__device__ __forceinline__ void glds16(const void* g, void* l) {
  __builtin_amdgcn_global_load_lds(
      (const __attribute__((address_space(1))) unsigned int*)g,
      (__attribute__((address_space(3))) unsigned int*)l, 16, 0, 0);
}

__device__ __forceinline__ u16 f2bf(float f) {
  unsigned int u = __builtin_bit_cast(unsigned int, f);
  u += 0x7fffu + ((u >> 16) & 1u);   // RNE (finite inputs)
  return (u16)(u >> 16);
}

// ---------------- prep: weight conversion only ----------------
__global__ __launch_bounds__(256) void prep_w(
    const float* __restrict__ We, const float* __restrict__ Wt,
    const float* __restrict__ Wg,
    u16* __restrict__ We_bf, u16* __restrict__ Wt_bf,
    u16* __restrict__ Wg_hi, u16* __restrict__ Wg_lo) {
  const int bx = blockIdx.x;
  if (bx < 520) {
    const float* src; u16* dst;
    if (bx < 512) { int base = bx * 2048 + threadIdx.x * 8; src = We + base; dst = We_bf + base; }
    else { int base = (bx - 512) * 2048 + threadIdx.x * 8; src = Wt + base; dst = Wt_bf + base; }
    float4 a = *(const float4*)src;
    float4 b = *(const float4*)(src + 4);
    uint4 o;
    o.x = (unsigned)f2bf(a.x) | ((unsigned)f2bf(a.y) << 16);
    o.y = (unsigned)f2bf(a.z) | ((unsigned)f2bf(a.w) << 16);
    o.z = (unsigned)f2bf(b.x) | ((unsigned)f2bf(b.y) << 16);
    o.w = (unsigned)f2bf(b.z) | ((unsigned)f2bf(b.w) << 16);
    *(uint4*)dst = o;
  } else {
    int base = (bx - 520) * 2048 + threadIdx.x * 8;
    float x[8];
    float4 a = *(const float4*)(Wg + base);
    float4 b = *(const float4*)(Wg + base + 4);
    x[0]=a.x; x[1]=a.y; x[2]=a.z; x[3]=a.w; x[4]=b.x; x[5]=b.y; x[6]=b.z; x[7]=b.w;
    u16 h[8], l[8];
#pragma unroll
    for (int j = 0; j < 8; j++) {
      h[j] = f2bf(x[j]);
      float hf = __builtin_bit_cast(float, ((unsigned)h[j]) << 16);
      l[j] = f2bf(x[j] - hf);
    }
    uint4 oh, ol;
    oh.x = (unsigned)h[0] | ((unsigned)h[1] << 16);
    oh.y = (unsigned)h[2] | ((unsigned)h[3] << 16);
    oh.z = (unsigned)h[4] | ((unsigned)h[5] << 16);
    oh.w = (unsigned)h[6] | ((unsigned)h[7] << 16);
    ol.x = (unsigned)l[0] | ((unsigned)l[1] << 16);
    ol.y = (unsigned)l[2] | ((unsigned)l[3] << 16);
    ol.z = (unsigned)l[4] | ((unsigned)l[5] << 16);
    ol.w = (unsigned)l[6] | ((unsigned)l[7] << 16);
    *(uint4*)(Wg_hi + base) = oh;
    *(uint4*)(Wg_lo + base) = ol;
  }
}

// stage one B chunk (128 h-rows x 64 k, bf16, 16 KB) via glds16.
// t = e*16 + kc*2 + half. Pre-swizzled source: LDS slot s of row n holds
// source granule g = s ^ (n&7); reader uses slot = g ^ (n&7).
// 4 glds16 per thread per call -> vmcnt counting unit = 4.
__device__ __forceinline__ void stage_chunk(const u16* __restrict__ We_bf,
                                            u16* buf, int t, int tid) {
  const int e_ = t >> 4, kc_ = (t >> 1) & 7, half_ = t & 1;
  const u16* src = We_bf + (e_ << 17) + (half_ << 16) + (kc_ << 6);
#pragma unroll
  for (int r = 0; r < 4; r++) {
    int gi = r * 256 + tid;             // 0..1023 granules
    int n = gi >> 3, s = gi & 7;
    int g = s ^ (n & 7);
    glds16(src + (n << 9) + (g << 3), buf + (gi << 3));
  }
}

// ---------------- fused main kernel ----------------
// grid = 512 (32-row m-tiles, FULL H=256), 256 threads = 4 waves (64-col
// bands of the active 128-row h-half). A (xv) lives in LDS (32 KB,
// XOR-swizzled, written ONCE by wave 0 in the prologue) — NOT in registers:
// reg-resident A (r1-r5) always spilled ~40 regs (arch/acc split pins arch
// at 128; 24 MB scratch writes, reloads on the MFMA critical path).
// B (We) streams through a 3-buffer, depth-2-prefetch LDS pipeline with
// COUNTED vmcnt + raw s_barrier (fused in one asm): loads stay in flight
// across barriers. vmcnt(4) steady (see macro comment — vmcnt(8) was the
// r6 race), vmcnt(0) only at the very last chunk. No sched_barrier (r4
// regression = m141 order-pinning). Fold's be loads are the newest VMEM at
// their use -> implicit full drain once per expert (known, accepted: be in
// LDS would break the 80 KB 2-blocks/CU budget; be in regs needs runtime-e
// indexing = rule #20 scratch).
// LDS = 32 (A) + 3*16 (B) = 80 KB -> 2 blocks/CU.
__global__ __launch_bounds__(256, 2) void moe_main(
    const float* __restrict__ xv, const u16* __restrict__ We_bf,
    const float* __restrict__ be, const float* __restrict__ bg,
    const u16* __restrict__ Wg_hi, const u16* __restrict__ Wg_lo,
    const u16* __restrict__ Wt_bf, const float* __restrict__ bt,
    float* __restrict__ out) {
  __shared__ u16 lds[40960];            // 80 KB: A[16384] + 3 x B[8192]

  const int tid = threadIdx.x;
  const int lane = tid & 63;
  const int wid = tid >> 6;             // 0..3
  const int wn = wid;                   // 64-col band within active h-half
  const int l15 = lane & 15;
  const int l4 = lane >> 4;             // 0..3
  const int m0 = blockIdx.x << 5;       // 32 rows per block

  // prefetch chunks 0,1 into bufs 0,1 — land during the prologue
  stage_chunk(We_bf, &lds[16384], 0, tid);
  stage_chunk(We_bf, &lds[16384 + 8192], 1, tid);

  // ---- prologue: A f32 -> bf16 into LDS (wave 0) + gate via hi/lo MFMA ----
  // Every wave converts (needs its own gate logits); only wave 0 writes A.
  f32x4 g0[2] = {{0.f,0.f,0.f,0.f},{0.f,0.f,0.f,0.f}};
  f32x4 g1[2] = {{0.f,0.f,0.f,0.f},{0.f,0.f,0.f,0.f}};
  f32x4 g2[2] = {{0.f,0.f,0.f,0.f},{0.f,0.f,0.f,0.f}};
  const int esrc = l15 & 7;
#pragma unroll
  for (int mt = 0; mt < 2; mt++) {
#pragma unroll
    for (int ks = 0; ks < 16; ks++) {
      const int row = mt * 16 + l15;
      const float* ap = xv + ((m0 + row) << 9) + ks * 32 + l4 * 8;
      float4 xa = *(const float4*)ap;
      float4 xb = *(const float4*)(ap + 4);
      float x[8];
      x[0]=xa.x; x[1]=xa.y; x[2]=xa.z; x[3]=xa.w; x[4]=xb.x; x[5]=xb.y; x[6]=xb.z; x[7]=xb.w;
      bf16x8 hv, lv;
#pragma unroll
      for (int j = 0; j < 8; j++) {
        u16 hb_ = f2bf(x[j]);
        float hf = __builtin_bit_cast(float, ((unsigned)hb_) << 16);
        hv[j] = __builtin_bit_cast(__bf16, hb_);
        lv[j] = __builtin_bit_cast(__bf16, f2bf(x[j] - hf));
      }
      if (wid == 0) {
        int gA = ks * 4 + l4;           // 0..63 k-granule
        int slotA = (gA & ~7) | ((gA & 7) ^ (row & 7));
        *(bf16x8*)&lds[(row << 9) + (slotA << 3)] = hv;
      }
      bf16x8 wh = *(const bf16x8*)(Wg_hi + (esrc << 9) + ks * 32 + l4 * 8);
      bf16x8 wl = *(const bf16x8*)(Wg_lo + (esrc << 9) + ks * 32 + l4 * 8);
      g0[mt] = __builtin_amdgcn_mfma_f32_16x16x32_bf16(hv, wh, g0[mt], 0, 0, 0);
      g1[mt] = __builtin_amdgcn_mfma_f32_16x16x32_bf16(lv, wh, g1[mt], 0, 0, 0);
      g2[mt] = __builtin_amdgcn_mfma_f32_16x16x32_bf16(hv, wl, g2[mt], 0, 0, 0);
    }
  }
  // softmax over experts (lane holds logit[row=l4*4+i][e=l15&7])
  float gv[2][4];
  {
    float bgv = bg[esrc];
#pragma unroll
    for (int mt = 0; mt < 2; mt++)
#pragma unroll
      for (int i = 0; i < 4; i++) {
        float z = g0[mt][i] + g1[mt][i] + g2[mt][i] + bgv;
        float mx = z;
        mx = fmaxf(mx, __shfl_xor(mx, 1));
        mx = fmaxf(mx, __shfl_xor(mx, 2));
        mx = fmaxf(mx, __shfl_xor(mx, 4));
        float p = __expf(z - mx);
        float s = p;
        s += __shfl_xor(s, 1);
        s += __shfl_xor(s, 2);
        s += __shfl_xor(s, 4);
        gv[mt][i] = p / s;
      }
  }
  // publish A-tile (drain wave-0 ds_writes, barrier) WITHOUT draining vmcnt
  asm volatile("s_waitcnt lgkmcnt(0)\ns_barrier" ::: "memory");

  // ---- expert loop: counted-vmcnt 3-buffer B pipeline, A-frags from LDS ----
  f32x4 comb[2][4];
#pragma unroll
  for (int mt = 0; mt < 2; mt++)
#pragma unroll
    for (int nt = 0; nt < 4; nt++) comb[mt][nt] = {0.f, 0.f, 0.f, 0.f};

  int bcur = 0;                         // rotating buffer index for chunk t
#pragma unroll 1
  for (int e = 0; e < 8; e++) {
    f32x4 acc[2][4];
#pragma unroll
    for (int mt = 0; mt < 2; mt++)
#pragma unroll
      for (int nt = 0; nt < 4; nt++) acc[mt][nt] = {0.f, 0.f, 0.f, 0.f};

#pragma unroll
    for (int kc = 0; kc < 8; kc++) {
      // A-fragments for this kc (A-tile is stable; shared by both halves)
      bf16x8 af[2][2];
#pragma unroll
      for (int mt = 0; mt < 2; mt++)
#pragma unroll
        for (int ks = 0; ks < 2; ks++) {
          int gA = (kc * 2 + ks) * 4 + l4;
          int row = mt * 16 + l15;
          int slotA = (gA & ~7) | ((gA & 7) ^ (row & 7));
          af[mt][ks] = *(const bf16x8*)&lds[(row << 9) + (slotA << 3)];
        }
#pragma unroll
      for (int half = 0; half < 2; half++) {
        // counted wait (see macro comment): vmcnt(4) proves chunk t retired
        // with chunk t+1 in flight; only the final chunk needs a full drain.
        if (kc == 7 && e == 7 && half == 1) { BAR_V0; } else { BAR_V4; }
        int t2 = e * 16 + kc * 2 + half + 2;
        int bstage = bcur >= 1 ? bcur - 1 : 2;   // (bcur+2)%3
        if (t2 < 128)
          stage_chunk(We_bf, &lds[16384 + (bstage << 13)], t2, tid);
        const u16* Bb = &lds[16384 + (bcur << 13)];
#pragma unroll
        for (int ks = 0; ks < 2; ks++) {
#pragma unroll
          for (int ntl = 0; ntl < 2; ntl++) {
            int n = wn * 32 + ntl * 16 + l15;    // 0..127 in this half
            int gB = ks * 4 + l4;
            int slot = gB ^ (n & 7);
            bf16x8 bfr = *(const bf16x8*)&Bb[(n << 6) + (slot << 3)];
#pragma unroll
            for (int mt = 0; mt < 2; mt++)
              acc[mt][half * 2 + ntl] = __builtin_amdgcn_mfma_f32_16x16x32_bf16(
                  af[mt][ks], bfr, acc[mt][half * 2 + ntl], 0, 0, 0);
          }
        }
        bcur = bcur == 2 ? 0 : bcur + 1;
      }
    }
    // fold: comb += gate[row,e] * relu(acc + be[e,h]); be from global (L2)
    float bev[4];
#pragma unroll
    for (int j = 0; j < 4; j++)
      bev[j] = be[(e << 8) + (j >> 1) * 128 + wn * 32 + (j & 1) * 16 + l15];
#pragma unroll
    for (int mt = 0; mt < 2; mt++)
#pragma unroll
      for (int i = 0; i < 4; i++) {
        float g = __shfl(gv[mt][i], (lane & 48) | e);
#pragma unroll
        for (int j = 0; j < 4; j++)
          comb[mt][j][i] += g * fmaxf(acc[mt][j][i] + bev[j], 0.f);
      }
  }

  // ---- tower: comb[32x256] (bf16 via LDS, reusing A region) ----
  __syncthreads();                      // all waves done with A-tile/B-bufs
#pragma unroll
  for (int mt = 0; mt < 2; mt++)
#pragma unroll
    for (int i = 0; i < 4; i++) {
      int row = mt * 16 + l4 * 4 + i;
#pragma unroll
      for (int j = 0; j < 4; j++) {
        int col = (j >> 1) * 128 + wn * 32 + (j & 1) * 16 + l15;
        __bf16 v = (__bf16)comb[mt][j][i];
        lds[row * 264 + col] = __builtin_bit_cast(u16, v);   // pad 264
      }
    }
  __syncthreads();
  if (wid < 2) {
    f32x4 tacc[4];
#pragma unroll
    for (int nt = 0; nt < 4; nt++) tacc[nt] = {0.f, 0.f, 0.f, 0.f};
#pragma unroll
    for (int ks = 0; ks < 8; ks++) {
      bf16x8 aT = *(const bf16x8*)&lds[(wid * 16 + l15) * 264 + ks * 32 + l4 * 8];
#pragma unroll
      for (int nt = 0; nt < 4; nt++) {
        bf16x8 bT = *(const bf16x8*)&Wt_bf[(nt * 16 + l15) * 256 + ks * 32 + l4 * 8];
        tacc[nt] = __builtin_amdgcn_mfma_f32_16x16x32_bf16(aT, bT, tacc[nt], 0, 0, 0);
      }
    }
#pragma unroll
    for (int nt = 0; nt < 4; nt++) {
      float btv = bt[nt * 16 + l15];
#pragma unroll
      for (int i = 0; i < 4; i++) {
        int row = m0 + wid * 16 + l4 * 4 + i;
        float v = tacc[nt][i] + btv;
        out[row * 64 + nt * 16 + l15] = 1.f / (1.f + __expf(-v));
      }
    }
  }
}

extern "C" void kernel_launch(void* const* d_in, const int* in_sizes, int n_in,
                              void* d_out, int out_size, void* d_ws, size_t ws_size,
                              hipStream_t stream) {
  const float* xv = (const float*)d_in[0];
  const float* We = (const float*)d_in[1];
  const float* be = (const float*)d_in[2];
  const float* Wg = (const float*)d_in[3];
  const float* bg = (const float*)d_in[4];
  const float* Wt = (const float*)d_in[5];
  const float* bt = (const float*)d_in[6];

  char* ws = (char*)d_ws;
  u16* We_bf = (u16*)ws;                        // 2 MB   (8*256*512 bf16)
  u16* Wt_bf = (u16*)(ws + 2097152);            // 32 KB  (64*256 bf16)
  u16* Wg_hi = (u16*)(ws + 2129920);            // 8 KB   (8*512 bf16)
  u16* Wg_lo = (u16*)(ws + 2138112);            // 8 KB

  prep_w<<<522, 256, 0, stream>>>(We, Wt, Wg, We_bf, Wt_bf, Wg_hi, Wg_lo);
  moe_main<<<512, 256, 0, stream>>>(xv, We_bf, be, bg, Wg_hi, Wg_lo, Wt_bf, bt,
                                    (float*)d_out);
}